// Round 14
// baseline (517.013 us; speedup 1.0000x reference)
//
#include <hip/hip_runtime.h>
#include <math.h>

#define NN 50000
#define NE 1600000
#define DIN 512
#define HH 128
#define EPSBN 1e-5f
#define NB 782        // ceil(NN/64) buckets of 64 nodes
#define PAD 16        // ints per bucket counter: one 64B line each
#define CAPE 4096     // per-bucket edge capacity (mean 2046)
#define CHUNK 6144    // edges per k_part/k_hist block
#define NBLK ((NE + CHUNK - 1) / CHUNK)

typedef __attribute__((ext_vector_type(8))) short bf16x8;
typedef __attribute__((ext_vector_type(4))) float f32x4;

__device__ __forceinline__ unsigned short f2bf(float f) {
    unsigned u = __builtin_bit_cast(unsigned, f);
    u += 0x7FFFu + ((u >> 16) & 1u);   // RNE
    return (unsigned short)(u >> 16);
}
__device__ __forceinline__ unsigned packbf(float a, float b) {
    return (unsigned)f2bf(a) | ((unsigned)f2bf(b) << 16);
}
__device__ __forceinline__ float bf2f(unsigned short v) {
    return __builtin_bit_cast(float, (unsigned)v << 16);
}

// stats layout (line-padded): sums at st[col*16], sumsq at st[2048 + col*16]; 4096 floats/layer

// ---------------- zero padded bucket counts + padded BN stat accumulators ----------------
__global__ void k_zero(int* __restrict__ bcnt, float* __restrict__ st) {
    int i = blockIdx.x * 256 + threadIdx.x;
    if (i < NB * PAD) bcnt[i] = 0;
    if (i < 8192) st[i] = 0.0f;    // 2 layers x 4096 padded floats
}

// ---------------- bucket count: LDS-aggregated histogram ----------------
__global__ __launch_bounds__(256) void k_hist(const int* __restrict__ dst,
                                              int* __restrict__ bcnt) {
    __shared__ int h[1024];
    int t = threadIdx.x;
    for (int i = t; i < 1024; i += 256) h[i] = 0;
    __syncthreads();
    int eb = blockIdx.x * CHUNK;
    int cnt = NE - eb;
    if (cnt > CHUNK) cnt = CHUNK;
    for (int i = t; i < cnt; i += 256) atomicAdd(&h[dst[eb + i] >> 6], 1);
    __syncthreads();
    for (int b = t; b < NB; b += 256) {
        int c = h[b];
        if (c) atomicAdd(&bcnt[b << 4], c);
    }
}

// ---------------- bucket scan; bcnt becomes cursor ----------------
__global__ __launch_bounds__(1024) void k_bscan(int* __restrict__ bcnt,
                                                int* __restrict__ bbase,
                                                int* __restrict__ rowptr) {
    __shared__ int ps[1024];
    int t = threadIdx.x;
    int v = (t < NB) ? bcnt[t << 4] : 0;
    ps[t] = v;
    __syncthreads();
    for (int off = 1; off < 1024; off <<= 1) {
        int u = (t >= off) ? ps[t - off] : 0;
        __syncthreads();
        ps[t] += u;
        __syncthreads();
    }
    int ex = ps[t] - v;
    bbase[t] = ex;
    if (t < NB) bcnt[t << 4] = ex;
    if (t == 0) rowptr[NN] = NE;   // sentinel
}

// ---------------- LDS-staged multisplit (packed UNSIGNED: b<<22 | (dst&63)<<16 | src) ----------------
__global__ __launch_bounds__(256) void k_part(const int* __restrict__ src,
                                              const int* __restrict__ dst,
                                              int* __restrict__ bcursor,
                                              unsigned* __restrict__ packed) {
    __shared__ unsigned stage[CHUNK];
    __shared__ unsigned stage2[CHUNK];
    __shared__ int hist[1024];
    __shared__ int prefix[1024];
    __shared__ int baseg[1024];
    __shared__ int ps[256];
    int t = threadIdx.x;
    int eb = blockIdx.x * CHUNK;
    int cnt = NE - eb;
    if (cnt > CHUNK) cnt = CHUNK;

    for (int i = t; i < 1024; i += 256) hist[i] = 0;
    __syncthreads();
    for (int i = t; i < cnt; i += 256) {
        int e = eb + i;
        unsigned s = (unsigned)src[e];
        unsigned d = (unsigned)dst[e];
        unsigned b = d >> 6;
        stage[i] = (b << 22) | ((d & 63u) << 16) | s;
        atomicAdd(&hist[b], 1);
    }
    __syncthreads();
    int b0 = t * 4;
    int h0 = hist[b0], h1 = hist[b0 + 1], h2 = hist[b0 + 2], h3 = hist[b0 + 3];
    int tot = h0 + h1 + h2 + h3;
    ps[t] = tot;
    __syncthreads();
    for (int off = 1; off < 256; off <<= 1) {
        int u = (t >= off) ? ps[t - off] : 0;
        __syncthreads();
        ps[t] += u;
        __syncthreads();
    }
    int ex = ps[t] - tot;
    prefix[b0] = ex;
    prefix[b0 + 1] = ex + h0;
    prefix[b0 + 2] = ex + h0 + h1;
    prefix[b0 + 3] = ex + h0 + h1 + h2;
    __syncthreads();
    for (int b = t; b < 1024; b += 256) {
        int c = hist[b];
        if (c > 0 && b < NB) baseg[b] = atomicAdd(&bcursor[b << 4], c);
        hist[b] = prefix[b];
    }
    __syncthreads();
    for (int i = t; i < cnt; i += 256) {
        unsigned pk = stage[i];
        int p = atomicAdd(&hist[pk >> 22], 1);
        stage2[p] = pk;
    }
    __syncthreads();
    for (int i = t; i < cnt; i += 256) {
        unsigned pk = stage2[i];
        unsigned b = pk >> 22;
        packed[baseg[b] + (i - prefix[b])] = pk;
    }
}

// ---------------- per-bucket CSR finalize: writes epk=(dst<<16)|src, rowptr, dinv ----------------
__global__ __launch_bounds__(256) void k_bfinal(const unsigned* __restrict__ packed,
                                                const int* __restrict__ bbase,
                                                unsigned* __restrict__ epk,
                                                int* __restrict__ rowptr,
                                                float* __restrict__ dinv) {
    __shared__ unsigned pk[CAPE];
    __shared__ unsigned outv[CAPE];
    __shared__ int hcnt[64], hoff[64], hcur[64];
    int b = blockIdx.x;
    int base = bbase[b];
    int cnt = bbase[b + 1] - base;
    if (cnt > CAPE) cnt = CAPE;
    int t = threadIdx.x;
    for (int i = t; i < cnt; i += 256) pk[i] = packed[base + i];
    if (t < 64) hcnt[t] = 0;
    __syncthreads();
    for (int i = t; i < cnt; i += 256) atomicAdd(&hcnt[(pk[i] >> 16) & 63u], 1);
    __syncthreads();
    if (t == 0) {
        int run = 0;
        for (int i = 0; i < 64; ++i) { hoff[i] = run; hcur[i] = run; run += hcnt[i]; }
    }
    __syncthreads();
    if (t < 64) {
        int node = b * 64 + t;
        if (node < NN) {
            rowptr[node] = base + hoff[t];
            dinv[node] = rsqrtf((float)(hcnt[t] + 1));
        }
    }
    for (int i = t; i < cnt; i += 256) {
        unsigned v = pk[i] & 0x3FFFFFu;            // (dlocal<<16)|src
        int lpos = atomicAdd(&hcur[v >> 16], 1);
        outv[lpos] = v;
    }
    __syncthreads();
    const unsigned dbase = ((unsigned)(b * 64)) << 16;
    for (int i = t; i < cnt; i += 256)
        epk[base + i] = dbase + outv[i];           // (dst<<16)|src
}

// ---------------- merged prep: edge-parallel epk rewrite + weight transpose/bf16 ----------------
#define PREP_EBLKS ((NE + 255) / 256)   // 6250
__global__ void k_prep(const float* __restrict__ dinv, unsigned* __restrict__ epk,
                       const float* __restrict__ W1, const float* __restrict__ W2,
                       unsigned short* __restrict__ W1t, unsigned short* __restrict__ W2t) {
    int bid = blockIdx.x;
    if (bid < PREP_EBLKS) {
        int e = bid * 256 + threadIdx.x;
        if (e < NE) {
            unsigned pe = epk[e];
            unsigned s = pe & 0xFFFFu;
            unsigned d = pe >> 16;
            epk[e] = ((unsigned)f2bf(dinv[s] * dinv[d]) << 16) | s;
        }
    } else {
        int i = (bid - PREP_EBLKS) * 256 + threadIdx.x;
        if (i < 512 * 128) {
            int k = i >> 7, n = i & 127;
            W1t[n * 512 + k] = f2bf(W1[i]);
        }
        if (i < 128 * 128) {
            int k = i >> 7, n = i & 127;
            W2t[n * 128 + k] = f2bf(W2[i]);
        }
    }
}

// ---------------- GEMM1 (layer1): A f32 [M][512] @ W1t^T -> Cb[4][NN][32] bf16 ----------------
__global__ __launch_bounds__(256) void k_gemm1(const float* __restrict__ A,
                                               const unsigned short* __restrict__ Wt,
                                               unsigned short* __restrict__ Cb,
                                               int M, int K) {
    __shared__ unsigned short As[64][72];
    __shared__ unsigned short Bs[128][72];
    const int tid = threadIdx.x;
    const int m0 = blockIdx.x * 64;
    const int w = tid >> 6;
    const int lane = tid & 63;
    const int cr = lane & 15;
    const int half = lane >> 4;
    const int arow = tid >> 2;
    const int akseg = (tid & 3) << 4;
    const int brow = tid >> 1;
    const int bkseg = (tid & 1) << 5;

    f32x4 acc[8];
#pragma unroll
    for (int n = 0; n < 8; ++n) acc[n] = (f32x4){0.f, 0.f, 0.f, 0.f};

    for (int kc = 0; kc < K; kc += 64) {
        float4 va[4];
        int gm = m0 + arow;
        if (gm < M) {
            const float* ap = A + (size_t)gm * K + kc + akseg;
#pragma unroll
            for (int i = 0; i < 4; ++i) va[i] = ((const float4*)ap)[i];
        } else {
#pragma unroll
            for (int i = 0; i < 4; ++i) va[i] = make_float4(0.f, 0.f, 0.f, 0.f);
        }
        uint4 q0, q1;
        q0.x = packbf(va[0].x, va[0].y); q0.y = packbf(va[0].z, va[0].w);
        q0.z = packbf(va[1].x, va[1].y); q0.w = packbf(va[1].z, va[1].w);
        q1.x = packbf(va[2].x, va[2].y); q1.y = packbf(va[2].z, va[2].w);
        q1.z = packbf(va[3].x, va[3].y); q1.w = packbf(va[3].z, va[3].w);
        *(uint4*)(&As[arow][akseg]) = q0;
        *(uint4*)(&As[arow][akseg + 8]) = q1;
        {
            const unsigned short* wp = Wt + (size_t)brow * K + kc + bkseg;
            uint4* bp = (uint4*)(&Bs[brow][bkseg]);
#pragma unroll
            for (int i = 0; i < 4; ++i) bp[i] = ((const uint4*)wp)[i];
        }
        __syncthreads();
        const int wrow = w << 4;
#pragma unroll
        for (int ks = 0; ks < 2; ++ks) {
            bf16x8 af = *(const bf16x8*)(&As[wrow + cr][ks * 32 + half * 8]);
#pragma unroll
            for (int n = 0; n < 8; ++n) {
                bf16x8 bfr = *(const bf16x8*)(&Bs[n * 16 + cr][ks * 32 + half * 8]);
                acc[n] = __builtin_amdgcn_mfma_f32_16x16x32_bf16(af, bfr, acc[n], 0, 0, 0);
            }
        }
        __syncthreads();
    }
#pragma unroll
    for (int n = 0; n < 8; ++n) {
        int col = n * 16 + cr;
        size_t cbase = (size_t)(col >> 5) * NN * 32 + (col & 31);
#pragma unroll
        for (int reg = 0; reg < 4; ++reg) {
            int gr = m0 + (w << 4) + half * 4 + reg;
            if (gr < M) Cb[cbase + (size_t)gr * 32] = f2bf(acc[n][reg]);
        }
    }
}

// ---------------- GEMM2 (layer2): A bf16 [M][128], BN+ReLU inline (padded stats) ----------------
__global__ __launch_bounds__(256) void k_gemm2(const unsigned short* __restrict__ A,
                                               const unsigned short* __restrict__ Wt,
                                               const float* __restrict__ st,
                                               const float* __restrict__ gam,
                                               const float* __restrict__ beta,
                                               unsigned short* __restrict__ Cb,
                                               int M) {
    __shared__ unsigned short As[64][72];
    __shared__ unsigned short Bs[128][72];
    __shared__ float scs[128], shs[128];
    const int tid = threadIdx.x;
    const int m0 = blockIdx.x * 64;
    const int w = tid >> 6;
    const int lane = tid & 63;
    const int cr = lane & 15;
    const int half = lane >> 4;
    const int arow = tid >> 2;
    const int akseg = (tid & 3) << 4;
    const int brow = tid >> 1;
    const int bkseg = (tid & 1) << 5;

    if (tid < 128) {   // inline BN finalize from padded stats
        const float invn = 1.0f / (float)NN;
        float mu = st[tid * 16] * invn;
        float var = fmaf(-mu, mu, st[2048 + tid * 16] * invn);
        float s = gam[tid] * rsqrtf(var + EPSBN);
        scs[tid] = s;
        shs[tid] = fmaf(-mu, s, beta[tid]);
    }

    f32x4 acc[8];
#pragma unroll
    for (int n = 0; n < 8; ++n) acc[n] = (f32x4){0.f, 0.f, 0.f, 0.f};

    for (int kc = 0; kc < 128; kc += 64) {
        uint4 q0 = {0, 0, 0, 0}, q1 = {0, 0, 0, 0};
        int gm = m0 + arow;
        if (gm < M) {
            const uint4* ap = (const uint4*)(A + (size_t)gm * 128 + kc + akseg);
            q0 = ap[0];
            q1 = ap[1];
        }
        if (kc == 0) __syncthreads();  // scs/shs ready
        int kb = kc + akseg;
        unsigned qq[8] = {q0.x, q0.y, q0.z, q0.w, q1.x, q1.y, q1.z, q1.w};
#pragma unroll
        for (int j = 0; j < 8; ++j) {
            int k = kb + j * 2;
            float lo = fmaxf(fmaf(bf2f((unsigned short)(qq[j] & 0xFFFFu)), scs[k], shs[k]), 0.f);
            float hi = fmaxf(fmaf(bf2f((unsigned short)(qq[j] >> 16)), scs[k + 1], shs[k + 1]), 0.f);
            qq[j] = packbf(lo, hi);
        }
        *(uint4*)(&As[arow][akseg])     = make_uint4(qq[0], qq[1], qq[2], qq[3]);
        *(uint4*)(&As[arow][akseg + 8]) = make_uint4(qq[4], qq[5], qq[6], qq[7]);
        {
            const unsigned short* wp = Wt + (size_t)brow * 128 + kc + bkseg;
            uint4* bp = (uint4*)(&Bs[brow][bkseg]);
#pragma unroll
            for (int i = 0; i < 4; ++i) bp[i] = ((const uint4*)wp)[i];
        }
        __syncthreads();
        const int wrow = w << 4;
#pragma unroll
        for (int ks = 0; ks < 2; ++ks) {
            bf16x8 af = *(const bf16x8*)(&As[wrow + cr][ks * 32 + half * 8]);
#pragma unroll
            for (int n = 0; n < 8; ++n) {
                bf16x8 bfr = *(const bf16x8*)(&Bs[n * 16 + cr][ks * 32 + half * 8]);
                acc[n] = __builtin_amdgcn_mfma_f32_16x16x32_bf16(af, bfr, acc[n], 0, 0, 0);
            }
        }
        __syncthreads();
    }
#pragma unroll
    for (int n = 0; n < 8; ++n) {
        int col = n * 16 + cr;
        size_t cbase = (size_t)(col >> 5) * NN * 32 + (col & 31);
#pragma unroll
        for (int reg = 0; reg < 4; ++reg) {
            int gr = m0 + (w << 4) + half * 4 + reg;
            if (gr < M) Cb[cbase + (size_t)gr * 32] = f2bf(acc[n][reg]);
        }
    }
}

// ---------------- column-blocked CSR gather -> bf16 h, FUSED per-chunk BN stats ----------------
__global__ __launch_bounds__(256) void k_gather128b(const unsigned short* __restrict__ tb,
                                                    const int* __restrict__ rowptr,
                                                    const unsigned* __restrict__ epk,
                                                    const float* __restrict__ dinv,
                                                    const float* __restrict__ bias,
                                                    unsigned short* __restrict__ h,
                                                    float* __restrict__ stout,
                                                    int chunk) {
    int g = (blockIdx.x * 256 + threadIdx.x) >> 3;
    int lane8 = threadIdx.x & 7;
    int co = lane8 * 4;
    const unsigned short* tab = tb + (size_t)chunk * NN * 32;
    float ax = 0.f, ay = 0.f, az = 0.f, aw = 0.f;
    if (g < NN) {
        int beg = rowptr[g], end = rowptr[g + 1];
        float dd = dinv[g];
        ushort4 sv = *(const ushort4*)(tab + (size_t)g * 32 + co);
        float4 bv = *(const float4*)(bias + chunk * 32 + co);
        float wself = dd * dd;
        ax = fmaf(bf2f(sv.x), wself, bv.x);
        ay = fmaf(bf2f(sv.y), wself, bv.y);
        az = fmaf(bf2f(sv.z), wself, bv.z);
        aw = fmaf(bf2f(sv.w), wself, bv.w);
        int idx0 = beg + lane8;
        unsigned pe = (idx0 < end) ? epk[idx0] : 0u;
        for (int base = beg; base < end; base += 8) {
            int nidx = base + 8 + lane8;
            unsigned pe_next = (nidx < end) ? epk[nidx] : 0u;
#pragma unroll
            for (int j = 0; j < 8; ++j) {
                unsigned pj = __shfl(pe, j, 8);
                float w = bf2f((unsigned short)(pj >> 16));
                int s = (int)(pj & 0xFFFFu);
                ushort4 v = *(const ushort4*)(tab + (size_t)s * 32 + co);
                ax = fmaf(bf2f(v.x), w, ax);
                ay = fmaf(bf2f(v.y), w, ay);
                az = fmaf(bf2f(v.z), w, az);
                aw = fmaf(bf2f(v.w), w, aw);
            }
            pe = pe_next;
        }
        ushort4 o;
        o.x = f2bf(ax); o.y = f2bf(ay); o.z = f2bf(az); o.w = f2bf(aw);
        *(ushort4*)(h + (size_t)g * 128 + chunk * 32 + co) = o;
    }
    // ---- fused BN stats for this chunk's 32 columns ----
    float sx = ax * ax, sy = ay * ay, sz = az * az, sw = aw * aw;
#pragma unroll
    for (int m = 8; m < 64; m <<= 1) {   // butterfly over the 8 nodes within each wave
        ax += __shfl_xor(ax, m); ay += __shfl_xor(ay, m);
        az += __shfl_xor(az, m); aw += __shfl_xor(aw, m);
        sx += __shfl_xor(sx, m); sy += __shfl_xor(sy, m);
        sz += __shfl_xor(sz, m); sw += __shfl_xor(sw, m);
    }
    __shared__ float ls[4][64];
    int wv = threadIdx.x >> 6;
    int lane = threadIdx.x & 63;
    if (lane < 8) {
        ls[wv][co + 0] = ax; ls[wv][co + 1] = ay;
        ls[wv][co + 2] = az; ls[wv][co + 3] = aw;
        ls[wv][32 + co + 0] = sx; ls[wv][32 + co + 1] = sy;
        ls[wv][32 + co + 2] = sz; ls[wv][32 + co + 3] = sw;
    }
    __syncthreads();
    int t = threadIdx.x;
    if (t < 64) {
        float v = ls[0][t] + ls[1][t] + ls[2][t] + ls[3][t];
        int c = chunk * 32 + (t & 31);
        atomicAdd(&stout[(t < 32) ? c * 16 : 2048 + c * 16], v);
    }
}

// ---------------- small GEMM, bf16 A, BN+ReLU inline (padded stats) ----------------
__global__ __launch_bounds__(256) void k_gemm8_bn(const unsigned short* __restrict__ A,
                                                  const float* __restrict__ W,
                                                  const float* __restrict__ st,
                                                  const float* __restrict__ gam,
                                                  const float* __restrict__ beta,
                                                  float* __restrict__ C, int M) {
    __shared__ float Ws[128 * 8];
    __shared__ float scs[128], shs[128];
    int tid = threadIdx.x;
    for (int i = tid; i < 128 * 8; i += 256) Ws[i] = W[i];
    if (tid < 128) {
        const float invn = 1.0f / (float)NN;
        float mu = st[tid * 16] * invn;
        float var = fmaf(-mu, mu, st[2048 + tid * 16] * invn);
        float s = gam[tid] * rsqrtf(var + EPSBN);
        scs[tid] = s;
        shs[tid] = fmaf(-mu, s, beta[tid]);
    }
    __syncthreads();
    int m = blockIdx.x * 32 + (tid >> 3);
    int n = tid & 7;
    if (m >= M) return;
    const unsigned short* a = A + (size_t)m * 128;
    float s = 0.0f;
#pragma unroll
    for (int k = 0; k < 128; k += 8) {
        uint4 q = *(const uint4*)(a + k);
        unsigned qq[4] = {q.x, q.y, q.z, q.w};
#pragma unroll
        for (int j = 0; j < 4; ++j) {
            int kk = k + j * 2;
            float lo = fmaxf(fmaf(bf2f((unsigned short)(qq[j] & 0xFFFFu)), scs[kk], shs[kk]), 0.f);
            float hi = fmaxf(fmaf(bf2f((unsigned short)(qq[j] >> 16)), scs[kk + 1], shs[kk + 1]), 0.f);
            s = fmaf(lo, Ws[kk * 8 + n], s);
            s = fmaf(hi, Ws[(kk + 1) * 8 + n], s);
        }
    }
    C[(size_t)m * 8 + n] = s;
}

// ---------------- CSR gather (8 cols) + fused log_softmax, shfl + prefetch ----------------
__global__ __launch_bounds__(256) void k_gather8_lsm(const float* __restrict__ t,
                                                     const int* __restrict__ rowptr,
                                                     const unsigned* __restrict__ epk,
                                                     const float* __restrict__ dinv,
                                                     const float* __restrict__ bias,
                                                     float* __restrict__ out) {
    int g = (blockIdx.x * 256 + threadIdx.x) >> 3;
    if (g >= NN) return;
    int c = threadIdx.x & 7;
    int beg = rowptr[g], end = rowptr[g + 1];
    float dd = dinv[g];
    float acc = fmaf(t[(size_t)g * 8 + c], dd * dd, bias[c]);
    int idx0 = beg + c;
    unsigned pe = (idx0 < end) ? epk[idx0] : 0u;
    for (int base = beg; base < end; base += 8) {
        int nidx = base + 8 + c;
        unsigned pe_next = (nidx < end) ? epk[nidx] : 0u;
#pragma unroll
        for (int j = 0; j < 8; ++j) {
            unsigned pj = __shfl(pe, j, 8);
            float w = bf2f((unsigned short)(pj >> 16));
            int s = (int)(pj & 0xFFFFu);
            acc = fmaf(t[(size_t)s * 8 + c], w, acc);
        }
        pe = pe_next;
    }
    float mx = acc;
#pragma unroll
    for (int m = 1; m < 8; m <<= 1) mx = fmaxf(mx, __shfl_xor(mx, m, 8));
    float ex = expf(acc - mx);
    float se = ex;
#pragma unroll
    for (int m = 1; m < 8; m <<= 1) se += __shfl_xor(se, m, 8);
    out[(size_t)g * 8 + c] = acc - (logf(se) + mx);
}

extern "C" void kernel_launch(void* const* d_in, const int* in_sizes, int n_in,
                              void* d_out, int out_size, void* d_ws, size_t ws_size,
                              hipStream_t stream) {
    const float* x     = (const float*)d_in[0];
    const int*   eidx  = (const int*)d_in[1];
    const float* W1    = (const float*)d_in[2];
    const float* b1    = (const float*)d_in[3];
    const float* W2    = (const float*)d_in[4];
    const float* b2    = (const float*)d_in[5];
    const float* W3    = (const float*)d_in[6];
    const float* b3    = (const float*)d_in[7];
    const float* g1    = (const float*)d_in[8];
    const float* beta1 = (const float*)d_in[9];
    const float* g2    = (const float*)d_in[10];
    const float* beta2 = (const float*)d_in[11];
    float* out = (float*)d_out;

    const int* src = eidx;
    const int* dst = eidx + NE;

    char* ws = (char*)d_ws;
    int*   bcnt    = (int*)ws;            ws += 51200 * 4;
    int*   bbase   = (int*)ws;            ws += 2048 * 4;
    int*   rowptr  = (int*)ws;            ws += 51200 * 4;
    float* dinv    = (float*)ws;          ws += 51200 * 4;
    float* st      = (float*)ws;          ws += 8192 * 4;    // padded: 2 layers x 4096
    unsigned* epk  = (unsigned*)ws;       ws += (size_t)NE * 4;
    unsigned short* W1t = (unsigned short*)ws;  ws += 128 * 512 * 2;
    unsigned short* W2t = (unsigned short*)ws;  ws += 128 * 128 * 2;
    unsigned short* Ab  = (unsigned short*)ws;  ws += (size_t)4 * NN * 32 * 2;  // blocked bf16
    unsigned short* Bf  = (unsigned short*)ws;  ws += (size_t)NN * 128 * 2;     // bf16 h
    float* C       = (float*)ws;
    unsigned* packed = (unsigned*)Ab;  // overlap: consumed by k_bfinal before gemm1 writes Ab

    // ---- CSR build ----
    k_zero<<<(NB * PAD + 255) / 256, 256, 0, stream>>>(bcnt, st);
    k_hist<<<NBLK, 256, 0, stream>>>(dst, bcnt);
    k_bscan<<<1, 1024, 0, stream>>>(bcnt, bbase, rowptr);
    k_part<<<NBLK, 256, 0, stream>>>(src, dst, bcnt, packed);
    k_bfinal<<<NB, 256, 0, stream>>>(packed, bbase, epk, rowptr, dinv);
    k_prep<<<PREP_EBLKS + 256, 256, 0, stream>>>(dinv, epk, W1, W2, W1t, W2t);

    const int ggrid = (NN * 8 + 255) / 256;

    // ---- layer 1 (stats fused into gathers) ----
    k_gemm1<<<(NN + 63) / 64, 256, 0, stream>>>(x, W1t, Ab, NN, DIN);
    for (int ch = 0; ch < 4; ++ch)
        k_gather128b<<<ggrid, 256, 0, stream>>>(Ab, rowptr, epk, dinv, b1, Bf, st, ch);

    // ---- layer 2 (BN1+ReLU inline in A-staging; stats fused into gathers) ----
    k_gemm2<<<(NN + 63) / 64, 256, 0, stream>>>(Bf, W2t, st, g1, beta1, Ab, NN);
    for (int ch = 0; ch < 4; ++ch)
        k_gather128b<<<ggrid, 256, 0, stream>>>(Ab, rowptr, epk, dinv, b2, Bf, st + 4096, ch);

    // ---- layer 3 (BN2+ReLU inline) ----
    k_gemm8_bn<<<(NN + 31) / 32, 256, 0, stream>>>(Bf, W3, st + 4096, g2, beta2, C, NN);
    k_gather8_lsm<<<(NN * 8 + 255) / 256, 256, 0, stream>>>(C, rowptr, epk, dinv, b3, out);
}

// Round 15
// 378.046 us; speedup vs baseline: 1.3676x; 1.3676x over previous
//
#include <hip/hip_runtime.h>
#include <math.h>

#define NN 50000
#define NE 1600000
#define DIN 512
#define HH 128
#define EPSBN 1e-5f
#define NB 782        // ceil(NN/64) buckets of 64 nodes
#define PAD 16        // ints per bucket counter: one 64B line each
#define CAPE 4096     // per-bucket edge capacity (mean 2046)
#define CHUNK 6144    // edges per k_part/k_hist block
#define NBLK ((NE + CHUNK - 1) / CHUNK)

typedef __attribute__((ext_vector_type(8))) short bf16x8;
typedef __attribute__((ext_vector_type(4))) float f32x4;

__device__ __forceinline__ unsigned short f2bf(float f) {
    unsigned u = __builtin_bit_cast(unsigned, f);
    u += 0x7FFFu + ((u >> 16) & 1u);   // RNE
    return (unsigned short)(u >> 16);
}
__device__ __forceinline__ unsigned packbf(float a, float b) {
    return (unsigned)f2bf(a) | ((unsigned)f2bf(b) << 16);
}
__device__ __forceinline__ float bf2f(unsigned short v) {
    return __builtin_bit_cast(float, (unsigned)v << 16);
}

// ---------------- zero padded bucket counts + BN stat accumulators ----------------
__global__ void k_zero(int* __restrict__ bcnt, float* __restrict__ st) {
    int i = blockIdx.x * 256 + threadIdx.x;
    if (i < NB * PAD) bcnt[i] = 0;
    if (i < 512) st[i] = 0.0f;
}

// ---------------- bucket count: LDS-aggregated histogram ----------------
__global__ __launch_bounds__(256) void k_hist(const int* __restrict__ dst,
                                              int* __restrict__ bcnt) {
    __shared__ int h[1024];
    int t = threadIdx.x;
    for (int i = t; i < 1024; i += 256) h[i] = 0;
    __syncthreads();
    int eb = blockIdx.x * CHUNK;
    int cnt = NE - eb;
    if (cnt > CHUNK) cnt = CHUNK;
    for (int i = t; i < cnt; i += 256) atomicAdd(&h[dst[eb + i] >> 6], 1);
    __syncthreads();
    for (int b = t; b < NB; b += 256) {
        int c = h[b];
        if (c) atomicAdd(&bcnt[b << 4], c);
    }
}

// ---------------- bucket scan; bcnt becomes cursor ----------------
__global__ __launch_bounds__(1024) void k_bscan(int* __restrict__ bcnt,
                                                int* __restrict__ bbase,
                                                int* __restrict__ rowptr) {
    __shared__ int ps[1024];
    int t = threadIdx.x;
    int v = (t < NB) ? bcnt[t << 4] : 0;
    ps[t] = v;
    __syncthreads();
    for (int off = 1; off < 1024; off <<= 1) {
        int u = (t >= off) ? ps[t - off] : 0;
        __syncthreads();
        ps[t] += u;
        __syncthreads();
    }
    int ex = ps[t] - v;
    bbase[t] = ex;
    if (t < NB) bcnt[t << 4] = ex;
    if (t == 0) rowptr[NN] = NE;   // sentinel
}

// ---------------- LDS-staged multisplit (packed UNSIGNED: b<<22 | (dst&63)<<16 | src) ----------------
__global__ __launch_bounds__(256) void k_part(const int* __restrict__ src,
                                              const int* __restrict__ dst,
                                              int* __restrict__ bcursor,
                                              unsigned* __restrict__ packed) {
    __shared__ unsigned stage[CHUNK];
    __shared__ unsigned stage2[CHUNK];
    __shared__ int hist[1024];
    __shared__ int prefix[1024];
    __shared__ int baseg[1024];
    __shared__ int ps[256];
    int t = threadIdx.x;
    int eb = blockIdx.x * CHUNK;
    int cnt = NE - eb;
    if (cnt > CHUNK) cnt = CHUNK;

    for (int i = t; i < 1024; i += 256) hist[i] = 0;
    __syncthreads();
    for (int i = t; i < cnt; i += 256) {
        int e = eb + i;
        unsigned s = (unsigned)src[e];
        unsigned d = (unsigned)dst[e];
        unsigned b = d >> 6;
        stage[i] = (b << 22) | ((d & 63u) << 16) | s;
        atomicAdd(&hist[b], 1);
    }
    __syncthreads();
    int b0 = t * 4;
    int h0 = hist[b0], h1 = hist[b0 + 1], h2 = hist[b0 + 2], h3 = hist[b0 + 3];
    int tot = h0 + h1 + h2 + h3;
    ps[t] = tot;
    __syncthreads();
    for (int off = 1; off < 256; off <<= 1) {
        int u = (t >= off) ? ps[t - off] : 0;
        __syncthreads();
        ps[t] += u;
        __syncthreads();
    }
    int ex = ps[t] - tot;
    prefix[b0] = ex;
    prefix[b0 + 1] = ex + h0;
    prefix[b0 + 2] = ex + h0 + h1;
    prefix[b0 + 3] = ex + h0 + h1 + h2;
    __syncthreads();
    for (int b = t; b < 1024; b += 256) {
        int c = hist[b];
        if (c > 0 && b < NB) baseg[b] = atomicAdd(&bcursor[b << 4], c);
        hist[b] = prefix[b];
    }
    __syncthreads();
    for (int i = t; i < cnt; i += 256) {
        unsigned pk = stage[i];
        int p = atomicAdd(&hist[pk >> 22], 1);
        stage2[p] = pk;
    }
    __syncthreads();
    for (int i = t; i < cnt; i += 256) {
        unsigned pk = stage2[i];
        unsigned b = pk >> 22;
        packed[baseg[b] + (i - prefix[b])] = pk;
    }
}

// ---------------- per-bucket CSR finalize: writes epk=(dst<<16)|src, rowptr, dinv ----------------
__global__ __launch_bounds__(256) void k_bfinal(const unsigned* __restrict__ packed,
                                                const int* __restrict__ bbase,
                                                unsigned* __restrict__ epk,
                                                int* __restrict__ rowptr,
                                                float* __restrict__ dinv) {
    __shared__ unsigned pk[CAPE];
    __shared__ unsigned outv[CAPE];
    __shared__ int hcnt[64], hoff[64], hcur[64];
    int b = blockIdx.x;
    int base = bbase[b];
    int cnt = bbase[b + 1] - base;
    if (cnt > CAPE) cnt = CAPE;
    int t = threadIdx.x;
    for (int i = t; i < cnt; i += 256) pk[i] = packed[base + i];
    if (t < 64) hcnt[t] = 0;
    __syncthreads();
    for (int i = t; i < cnt; i += 256) atomicAdd(&hcnt[(pk[i] >> 16) & 63u], 1);
    __syncthreads();
    if (t == 0) {
        int run = 0;
        for (int i = 0; i < 64; ++i) { hoff[i] = run; hcur[i] = run; run += hcnt[i]; }
    }
    __syncthreads();
    if (t < 64) {
        int node = b * 64 + t;
        if (node < NN) {
            rowptr[node] = base + hoff[t];
            dinv[node] = rsqrtf((float)(hcnt[t] + 1));
        }
    }
    for (int i = t; i < cnt; i += 256) {
        unsigned v = pk[i] & 0x3FFFFFu;            // (dlocal<<16)|src
        int lpos = atomicAdd(&hcur[v >> 16], 1);
        outv[lpos] = v;
    }
    __syncthreads();
    const unsigned dbase = ((unsigned)(b * 64)) << 16;
    for (int i = t; i < cnt; i += 256)
        epk[base + i] = dbase + outv[i];           // (dst<<16)|src
}

// ---------------- merged prep: edge-parallel epk rewrite + weight transpose/bf16 ----------------
#define PREP_EBLKS ((NE + 255) / 256)   // 6250
__global__ void k_prep(const float* __restrict__ dinv, unsigned* __restrict__ epk,
                       const float* __restrict__ W1, const float* __restrict__ W2,
                       unsigned short* __restrict__ W1t, unsigned short* __restrict__ W2t) {
    int bid = blockIdx.x;
    if (bid < PREP_EBLKS) {
        int e = bid * 256 + threadIdx.x;
        if (e < NE) {
            unsigned pe = epk[e];
            unsigned s = pe & 0xFFFFu;
            unsigned d = pe >> 16;
            epk[e] = ((unsigned)f2bf(dinv[s] * dinv[d]) << 16) | s;
        }
    } else {
        int i = (bid - PREP_EBLKS) * 256 + threadIdx.x;
        if (i < 512 * 128) {
            int k = i >> 7, n = i & 127;
            W1t[n * 512 + k] = f2bf(W1[i]);
        }
        if (i < 128 * 128) {
            int k = i >> 7, n = i & 127;
            W2t[n * 128 + k] = f2bf(W2[i]);
        }
    }
}

// ---------------- GEMM1 (layer1): A f32 [M][512] @ W1t^T -> Cb[4][NN][32] bf16 ----------------
__global__ __launch_bounds__(256) void k_gemm1(const float* __restrict__ A,
                                               const unsigned short* __restrict__ Wt,
                                               unsigned short* __restrict__ Cb,
                                               int M, int K) {
    __shared__ unsigned short As[64][72];
    __shared__ unsigned short Bs[128][72];
    const int tid = threadIdx.x;
    const int m0 = blockIdx.x * 64;
    const int w = tid >> 6;
    const int lane = tid & 63;
    const int cr = lane & 15;
    const int half = lane >> 4;
    const int arow = tid >> 2;
    const int akseg = (tid & 3) << 4;
    const int brow = tid >> 1;
    const int bkseg = (tid & 1) << 5;

    f32x4 acc[8];
#pragma unroll
    for (int n = 0; n < 8; ++n) acc[n] = (f32x4){0.f, 0.f, 0.f, 0.f};

    for (int kc = 0; kc < K; kc += 64) {
        float4 va[4];
        int gm = m0 + arow;
        if (gm < M) {
            const float* ap = A + (size_t)gm * K + kc + akseg;
#pragma unroll
            for (int i = 0; i < 4; ++i) va[i] = ((const float4*)ap)[i];
        } else {
#pragma unroll
            for (int i = 0; i < 4; ++i) va[i] = make_float4(0.f, 0.f, 0.f, 0.f);
        }
        uint4 q0, q1;
        q0.x = packbf(va[0].x, va[0].y); q0.y = packbf(va[0].z, va[0].w);
        q0.z = packbf(va[1].x, va[1].y); q0.w = packbf(va[1].z, va[1].w);
        q1.x = packbf(va[2].x, va[2].y); q1.y = packbf(va[2].z, va[2].w);
        q1.z = packbf(va[3].x, va[3].y); q1.w = packbf(va[3].z, va[3].w);
        *(uint4*)(&As[arow][akseg]) = q0;
        *(uint4*)(&As[arow][akseg + 8]) = q1;
        {
            const unsigned short* wp = Wt + (size_t)brow * K + kc + bkseg;
            uint4* bp = (uint4*)(&Bs[brow][bkseg]);
#pragma unroll
            for (int i = 0; i < 4; ++i) bp[i] = ((const uint4*)wp)[i];
        }
        __syncthreads();
        const int wrow = w << 4;
#pragma unroll
        for (int ks = 0; ks < 2; ++ks) {
            bf16x8 af = *(const bf16x8*)(&As[wrow + cr][ks * 32 + half * 8]);
#pragma unroll
            for (int n = 0; n < 8; ++n) {
                bf16x8 bfr = *(const bf16x8*)(&Bs[n * 16 + cr][ks * 32 + half * 8]);
                acc[n] = __builtin_amdgcn_mfma_f32_16x16x32_bf16(af, bfr, acc[n], 0, 0, 0);
            }
        }
        __syncthreads();
    }
#pragma unroll
    for (int n = 0; n < 8; ++n) {
        int col = n * 16 + cr;
        size_t cbase = (size_t)(col >> 5) * NN * 32 + (col & 31);
#pragma unroll
        for (int reg = 0; reg < 4; ++reg) {
            int gr = m0 + (w << 4) + half * 4 + reg;
            if (gr < M) Cb[cbase + (size_t)gr * 32] = f2bf(acc[n][reg]);
        }
    }
}

// ---------------- GEMM2 (layer2): A bf16 [M][128], BN+ReLU inline (stats from st) ----------------
__global__ __launch_bounds__(256) void k_gemm2(const unsigned short* __restrict__ A,
                                               const unsigned short* __restrict__ Wt,
                                               const float* __restrict__ st,
                                               const float* __restrict__ gam,
                                               const float* __restrict__ beta,
                                               unsigned short* __restrict__ Cb,
                                               int M) {
    __shared__ unsigned short As[64][72];
    __shared__ unsigned short Bs[128][72];
    __shared__ float scs[128], shs[128];
    const int tid = threadIdx.x;
    const int m0 = blockIdx.x * 64;
    const int w = tid >> 6;
    const int lane = tid & 63;
    const int cr = lane & 15;
    const int half = lane >> 4;
    const int arow = tid >> 2;
    const int akseg = (tid & 3) << 4;
    const int brow = tid >> 1;
    const int bkseg = (tid & 1) << 5;

    if (tid < 128) {   // inline BN finalize
        const float invn = 1.0f / (float)NN;
        float mu = st[tid] * invn;
        float var = fmaf(-mu, mu, st[tid + 128] * invn);
        float s = gam[tid] * rsqrtf(var + EPSBN);
        scs[tid] = s;
        shs[tid] = fmaf(-mu, s, beta[tid]);
    }

    f32x4 acc[8];
#pragma unroll
    for (int n = 0; n < 8; ++n) acc[n] = (f32x4){0.f, 0.f, 0.f, 0.f};

    for (int kc = 0; kc < 128; kc += 64) {
        uint4 q0 = {0, 0, 0, 0}, q1 = {0, 0, 0, 0};
        int gm = m0 + arow;
        if (gm < M) {
            const uint4* ap = (const uint4*)(A + (size_t)gm * 128 + kc + akseg);
            q0 = ap[0];
            q1 = ap[1];
        }
        if (kc == 0) __syncthreads();  // scs/shs ready
        int kb = kc + akseg;
        unsigned qq[8] = {q0.x, q0.y, q0.z, q0.w, q1.x, q1.y, q1.z, q1.w};
#pragma unroll
        for (int j = 0; j < 8; ++j) {
            int k = kb + j * 2;
            float lo = fmaxf(fmaf(bf2f((unsigned short)(qq[j] & 0xFFFFu)), scs[k], shs[k]), 0.f);
            float hi = fmaxf(fmaf(bf2f((unsigned short)(qq[j] >> 16)), scs[k + 1], shs[k + 1]), 0.f);
            qq[j] = packbf(lo, hi);
        }
        *(uint4*)(&As[arow][akseg])     = make_uint4(qq[0], qq[1], qq[2], qq[3]);
        *(uint4*)(&As[arow][akseg + 8]) = make_uint4(qq[4], qq[5], qq[6], qq[7]);
        {
            const unsigned short* wp = Wt + (size_t)brow * 128 + kc + bkseg;
            uint4* bp = (uint4*)(&Bs[brow][bkseg]);
#pragma unroll
            for (int i = 0; i < 4; ++i) bp[i] = ((const uint4*)wp)[i];
        }
        __syncthreads();
        const int wrow = w << 4;
#pragma unroll
        for (int ks = 0; ks < 2; ++ks) {
            bf16x8 af = *(const bf16x8*)(&As[wrow + cr][ks * 32 + half * 8]);
#pragma unroll
            for (int n = 0; n < 8; ++n) {
                bf16x8 bfr = *(const bf16x8*)(&Bs[n * 16 + cr][ks * 32 + half * 8]);
                acc[n] = __builtin_amdgcn_mfma_f32_16x16x32_bf16(af, bfr, acc[n], 0, 0, 0);
            }
        }
        __syncthreads();
    }
#pragma unroll
    for (int n = 0; n < 8; ++n) {
        int col = n * 16 + cr;
        size_t cbase = (size_t)(col >> 5) * NN * 32 + (col & 31);
#pragma unroll
        for (int reg = 0; reg < 4; ++reg) {
            int gr = m0 + (w << 4) + half * 4 + reg;
            if (gr < M) Cb[cbase + (size_t)gr * 32] = f2bf(acc[n][reg]);
        }
    }
}

// ---------------- column-blocked CSR gather -> bf16 h: TWO chunks sequentially per block ----------------
__global__ __launch_bounds__(256) void k_gather128b(const unsigned short* __restrict__ tb,
                                                    const int* __restrict__ rowptr,
                                                    const unsigned* __restrict__ epk,
                                                    const float* __restrict__ dinv,
                                                    const float* __restrict__ bias,
                                                    unsigned short* __restrict__ h,
                                                    int pass) {
    int g = (blockIdx.x * 256 + threadIdx.x) >> 3;
    if (g >= NN) return;
    int lane8 = threadIdx.x & 7;
    int co = lane8 * 4;
    int beg = rowptr[g], end = rowptr[g + 1];
    float dd = dinv[g];
    float wself = dd * dd;

#pragma unroll
    for (int cc = 0; cc < 2; ++cc) {
        int chunk = pass * 2 + cc;
        const unsigned short* tab = tb + (size_t)chunk * NN * 32;
        ushort4 sv = *(const ushort4*)(tab + (size_t)g * 32 + co);
        float4 bv = *(const float4*)(bias + chunk * 32 + co);
        float ax = fmaf(bf2f(sv.x), wself, bv.x);
        float ay = fmaf(bf2f(sv.y), wself, bv.y);
        float az = fmaf(bf2f(sv.z), wself, bv.z);
        float aw = fmaf(bf2f(sv.w), wself, bv.w);
        int idx0 = beg + lane8;
        unsigned pe = (idx0 < end) ? epk[idx0] : 0u;
        for (int base = beg; base < end; base += 8) {
            int nidx = base + 8 + lane8;
            unsigned pe_next = (nidx < end) ? epk[nidx] : 0u;
#pragma unroll
            for (int j = 0; j < 8; ++j) {
                unsigned pj = __shfl(pe, j, 8);
                float w = bf2f((unsigned short)(pj >> 16));
                int s = (int)(pj & 0xFFFFu);
                ushort4 v = *(const ushort4*)(tab + (size_t)s * 32 + co);
                ax = fmaf(bf2f(v.x), w, ax);
                ay = fmaf(bf2f(v.y), w, ay);
                az = fmaf(bf2f(v.z), w, az);
                aw = fmaf(bf2f(v.w), w, aw);
            }
            pe = pe_next;
        }
        ushort4 o;
        o.x = f2bf(ax); o.y = f2bf(ay); o.z = f2bf(az); o.w = f2bf(aw);
        *(ushort4*)(h + (size_t)g * 128 + chunk * 32 + co) = o;
    }
}

// ---------------- BN stats over bf16 h ----------------
__global__ __launch_bounds__(256) void k_bnstats(const unsigned short* __restrict__ h,
                                                 float* __restrict__ sums,
                                                 float* __restrict__ sumsq) {
    int c4 = (threadIdx.x & 31) * 4;
    int rg = threadIdx.x >> 5;
    float s1x = 0, s1y = 0, s1z = 0, s1w = 0;
    float s2x = 0, s2y = 0, s2z = 0, s2w = 0;
    for (int r = blockIdx.x * 8 + rg; r < NN; r += gridDim.x * 8) {
        ushort4 u = *(const ushort4*)(h + (size_t)r * 128 + c4);
        float vx = bf2f(u.x), vy = bf2f(u.y), vz = bf2f(u.z), vw = bf2f(u.w);
        s1x += vx; s1y += vy; s1z += vz; s1w += vw;
        s2x = fmaf(vx, vx, s2x);
        s2y = fmaf(vy, vy, s2y);
        s2z = fmaf(vz, vz, s2z);
        s2w = fmaf(vw, vw, s2w);
    }
    __shared__ float l1[256][4];
    __shared__ float l2[256][4];
    l1[threadIdx.x][0] = s1x; l1[threadIdx.x][1] = s1y;
    l1[threadIdx.x][2] = s1z; l1[threadIdx.x][3] = s1w;
    l2[threadIdx.x][0] = s2x; l2[threadIdx.x][1] = s2y;
    l2[threadIdx.x][2] = s2z; l2[threadIdx.x][3] = s2w;
    __syncthreads();
    if (rg == 0) {
        int lane = threadIdx.x & 31;
#pragma unroll
        for (int gg = 1; gg < 8; ++gg) {
            int o = gg * 32 + lane;
            s1x += l1[o][0]; s1y += l1[o][1]; s1z += l1[o][2]; s1w += l1[o][3];
            s2x += l2[o][0]; s2y += l2[o][1]; s2z += l2[o][2]; s2w += l2[o][3];
        }
        atomicAdd(&sums[c4 + 0], s1x);
        atomicAdd(&sums[c4 + 1], s1y);
        atomicAdd(&sums[c4 + 2], s1z);
        atomicAdd(&sums[c4 + 3], s1w);
        atomicAdd(&sumsq[c4 + 0], s2x);
        atomicAdd(&sumsq[c4 + 1], s2y);
        atomicAdd(&sumsq[c4 + 2], s2z);
        atomicAdd(&sumsq[c4 + 3], s2w);
    }
}

// ---------------- small GEMM, bf16 A, BN+ReLU inline: C[M][8] = relu(bn(A)) @ W3 ----------------
__global__ __launch_bounds__(256) void k_gemm8_bn(const unsigned short* __restrict__ A,
                                                  const float* __restrict__ W,
                                                  const float* __restrict__ st,
                                                  const float* __restrict__ gam,
                                                  const float* __restrict__ beta,
                                                  float* __restrict__ C, int M) {
    __shared__ float Ws[128 * 8];
    __shared__ float scs[128], shs[128];
    int tid = threadIdx.x;
    for (int i = tid; i < 128 * 8; i += 256) Ws[i] = W[i];
    if (tid < 128) {
        const float invn = 1.0f / (float)NN;
        float mu = st[tid] * invn;
        float var = fmaf(-mu, mu, st[tid + 128] * invn);
        float s = gam[tid] * rsqrtf(var + EPSBN);
        scs[tid] = s;
        shs[tid] = fmaf(-mu, s, beta[tid]);
    }
    __syncthreads();
    int m = blockIdx.x * 32 + (tid >> 3);
    int n = tid & 7;
    if (m >= M) return;
    const unsigned short* a = A + (size_t)m * 128;
    float s = 0.0f;
#pragma unroll
    for (int k = 0; k < 128; k += 8) {
        uint4 q = *(const uint4*)(a + k);
        unsigned qq[4] = {q.x, q.y, q.z, q.w};
#pragma unroll
        for (int j = 0; j < 4; ++j) {
            int kk = k + j * 2;
            float lo = fmaxf(fmaf(bf2f((unsigned short)(qq[j] & 0xFFFFu)), scs[kk], shs[kk]), 0.f);
            float hi = fmaxf(fmaf(bf2f((unsigned short)(qq[j] >> 16)), scs[kk + 1], shs[kk + 1]), 0.f);
            s = fmaf(lo, Ws[kk * 8 + n], s);
            s = fmaf(hi, Ws[(kk + 1) * 8 + n], s);
        }
    }
    C[(size_t)m * 8 + n] = s;
}

// ---------------- CSR gather (8 cols) + fused log_softmax, shfl + prefetch ----------------
__global__ __launch_bounds__(256) void k_gather8_lsm(const float* __restrict__ t,
                                                     const int* __restrict__ rowptr,
                                                     const unsigned* __restrict__ epk,
                                                     const float* __restrict__ dinv,
                                                     const float* __restrict__ bias,
                                                     float* __restrict__ out) {
    int g = (blockIdx.x * 256 + threadIdx.x) >> 3;
    if (g >= NN) return;
    int c = threadIdx.x & 7;
    int beg = rowptr[g], end = rowptr[g + 1];
    float dd = dinv[g];
    float acc = fmaf(t[(size_t)g * 8 + c], dd * dd, bias[c]);
    int idx0 = beg + c;
    unsigned pe = (idx0 < end) ? epk[idx0] : 0u;
    for (int base = beg; base < end; base += 8) {
        int nidx = base + 8 + c;
        unsigned pe_next = (nidx < end) ? epk[nidx] : 0u;
#pragma unroll
        for (int j = 0; j < 8; ++j) {
            unsigned pj = __shfl(pe, j, 8);
            float w = bf2f((unsigned short)(pj >> 16));
            int s = (int)(pj & 0xFFFFu);
            acc = fmaf(t[(size_t)s * 8 + c], w, acc);
        }
        pe = pe_next;
    }
    float mx = acc;
#pragma unroll
    for (int m = 1; m < 8; m <<= 1) mx = fmaxf(mx, __shfl_xor(mx, m, 8));
    float ex = expf(acc - mx);
    float se = ex;
#pragma unroll
    for (int m = 1; m < 8; m <<= 1) se += __shfl_xor(se, m, 8);
    out[(size_t)g * 8 + c] = acc - (logf(se) + mx);
}

extern "C" void kernel_launch(void* const* d_in, const int* in_sizes, int n_in,
                              void* d_out, int out_size, void* d_ws, size_t ws_size,
                              hipStream_t stream) {
    const float* x     = (const float*)d_in[0];
    const int*   eidx  = (const int*)d_in[1];
    const float* W1    = (const float*)d_in[2];
    const float* b1    = (const float*)d_in[3];
    const float* W2    = (const float*)d_in[4];
    const float* b2    = (const float*)d_in[5];
    const float* W3    = (const float*)d_in[6];
    const float* b3    = (const float*)d_in[7];
    const float* g1    = (const float*)d_in[8];
    const float* beta1 = (const float*)d_in[9];
    const float* g2    = (const float*)d_in[10];
    const float* beta2 = (const float*)d_in[11];
    float* out = (float*)d_out;

    const int* src = eidx;
    const int* dst = eidx + NE;

    char* ws = (char*)d_ws;
    int*   bcnt    = (int*)ws;            ws += 51200 * 4;
    int*   bbase   = (int*)ws;            ws += 2048 * 4;
    int*   rowptr  = (int*)ws;            ws += 51200 * 4;
    float* dinv    = (float*)ws;          ws += 51200 * 4;
    float* st      = (float*)ws;          ws += 512 * 4;     // st1 | st2
    unsigned* epk  = (unsigned*)ws;       ws += (size_t)NE * 4;
    unsigned short* W1t = (unsigned short*)ws;  ws += 128 * 512 * 2;
    unsigned short* W2t = (unsigned short*)ws;  ws += 128 * 128 * 2;
    unsigned short* Ab  = (unsigned short*)ws;  ws += (size_t)4 * NN * 32 * 2;  // blocked bf16
    unsigned short* Bf  = (unsigned short*)ws;  ws += (size_t)NN * 128 * 2;     // bf16 h
    float* C       = (float*)ws;
    unsigned* packed = (unsigned*)Ab;  // overlap: consumed by k_bfinal before gemm1 writes Ab

    // ---- CSR build ----
    k_zero<<<(NB * PAD + 255) / 256, 256, 0, stream>>>(bcnt, st);
    k_hist<<<NBLK, 256, 0, stream>>>(dst, bcnt);
    k_bscan<<<1, 1024, 0, stream>>>(bcnt, bbase, rowptr);
    k_part<<<NBLK, 256, 0, stream>>>(src, dst, bcnt, packed);
    k_bfinal<<<NB, 256, 0, stream>>>(packed, bbase, epk, rowptr, dinv);
    k_prep<<<PREP_EBLKS + 256, 256, 0, stream>>>(dinv, epk, W1, W2, W1t, W2t);

    const int ggrid = (NN * 8 + 255) / 256;

    // ---- layer 1 (2 gather dispatches, 2 chunks each) ----
    k_gemm1<<<(NN + 63) / 64, 256, 0, stream>>>(x, W1t, Ab, NN, DIN);
    for (int p = 0; p < 2; ++p)
        k_gather128b<<<ggrid, 256, 0, stream>>>(Ab, rowptr, epk, dinv, b1, Bf, p);
    k_bnstats<<<512, 256, 0, stream>>>(Bf, st, st + 128);

    // ---- layer 2 (BN1+ReLU inline in A-staging) ----
    k_gemm2<<<(NN + 63) / 64, 256, 0, stream>>>(Bf, W2t, st, g1, beta1, Ab, NN);
    for (int p = 0; p < 2; ++p)
        k_gather128b<<<ggrid, 256, 0, stream>>>(Ab, rowptr, epk, dinv, b2, Bf, p);
    k_bnstats<<<512, 256, 0, stream>>>(Bf, st + 256, st + 384);

    // ---- layer 3 (BN2+ReLU inline) ----
    k_gemm8_bn<<<(NN + 31) / 32, 256, 0, stream>>>(Bf, W3, st + 256, g2, beta2, C, NN);
    k_gather8_lsm<<<(NN * 8 + 255) / 256, 256, 0, stream>>>(C, rowptr, epk, dinv, b3, out);
}

// Round 16
// 371.136 us; speedup vs baseline: 1.3931x; 1.0186x over previous
//
#include <hip/hip_runtime.h>
#include <math.h>

#define NN 50000
#define NE 1600000
#define DIN 512
#define HH 128
#define EPSBN 1e-5f
#define NB 782        // ceil(NN/64) buckets of 64 nodes
#define PAD 16        // ints per bucket counter: one 64B line each
#define CAPE 4096     // per-bucket edge capacity (mean 2046)
#define CHUNK 6144    // edges per k_part/k_hist block
#define NBLK ((NE + CHUNK - 1) / CHUNK)

typedef __attribute__((ext_vector_type(8))) short bf16x8;
typedef __attribute__((ext_vector_type(4))) float f32x4;
typedef _Float16 f16;
typedef __attribute__((ext_vector_type(2))) _Float16 f16x2;

__device__ __forceinline__ unsigned short f2bf(float f) {
    unsigned u = __builtin_bit_cast(unsigned, f);
    u += 0x7FFFu + ((u >> 16) & 1u);   // RNE
    return (unsigned short)(u >> 16);
}
__device__ __forceinline__ unsigned packbf(float a, float b) {
    return (unsigned)f2bf(a) | ((unsigned)f2bf(b) << 16);
}
__device__ __forceinline__ unsigned short f2h(float f) {
    return __builtin_bit_cast(unsigned short, (f16)f);
}
__device__ __forceinline__ float h2f(unsigned short v) {
    return (float)__builtin_bit_cast(f16, v);
}

// ---------------- zero padded bucket counts + BN stat accumulators ----------------
__global__ void k_zero(int* __restrict__ bcnt, float* __restrict__ st) {
    int i = blockIdx.x * 256 + threadIdx.x;
    if (i < NB * PAD) bcnt[i] = 0;
    if (i < 512) st[i] = 0.0f;
}

// ---------------- bucket count: LDS-aggregated histogram ----------------
__global__ __launch_bounds__(256) void k_hist(const int* __restrict__ dst,
                                              int* __restrict__ bcnt) {
    __shared__ int h[1024];
    int t = threadIdx.x;
    for (int i = t; i < 1024; i += 256) h[i] = 0;
    __syncthreads();
    int eb = blockIdx.x * CHUNK;
    int cnt = NE - eb;
    if (cnt > CHUNK) cnt = CHUNK;
    for (int i = t; i < cnt; i += 256) atomicAdd(&h[dst[eb + i] >> 6], 1);
    __syncthreads();
    for (int b = t; b < NB; b += 256) {
        int c = h[b];
        if (c) atomicAdd(&bcnt[b << 4], c);
    }
}

// ---------------- bucket scan; bcnt becomes cursor ----------------
__global__ __launch_bounds__(1024) void k_bscan(int* __restrict__ bcnt,
                                                int* __restrict__ bbase,
                                                int* __restrict__ rowptr) {
    __shared__ int ps[1024];
    int t = threadIdx.x;
    int v = (t < NB) ? bcnt[t << 4] : 0;
    ps[t] = v;
    __syncthreads();
    for (int off = 1; off < 1024; off <<= 1) {
        int u = (t >= off) ? ps[t - off] : 0;
        __syncthreads();
        ps[t] += u;
        __syncthreads();
    }
    int ex = ps[t] - v;
    bbase[t] = ex;
    if (t < NB) bcnt[t << 4] = ex;
    if (t == 0) rowptr[NN] = NE;   // sentinel
}

// ---------------- LDS-staged multisplit (packed UNSIGNED: b<<22 | (dst&63)<<16 | src) ----------------
__global__ __launch_bounds__(256) void k_part(const int* __restrict__ src,
                                              const int* __restrict__ dst,
                                              int* __restrict__ bcursor,
                                              unsigned* __restrict__ packed) {
    __shared__ unsigned stage[CHUNK];
    __shared__ unsigned stage2[CHUNK];
    __shared__ int hist[1024];
    __shared__ int prefix[1024];
    __shared__ int baseg[1024];
    __shared__ int ps[256];
    int t = threadIdx.x;
    int eb = blockIdx.x * CHUNK;
    int cnt = NE - eb;
    if (cnt > CHUNK) cnt = CHUNK;

    for (int i = t; i < 1024; i += 256) hist[i] = 0;
    __syncthreads();
    for (int i = t; i < cnt; i += 256) {
        int e = eb + i;
        unsigned s = (unsigned)src[e];
        unsigned d = (unsigned)dst[e];
        unsigned b = d >> 6;
        stage[i] = (b << 22) | ((d & 63u) << 16) | s;
        atomicAdd(&hist[b], 1);
    }
    __syncthreads();
    int b0 = t * 4;
    int h0 = hist[b0], h1 = hist[b0 + 1], h2 = hist[b0 + 2], h3 = hist[b0 + 3];
    int tot = h0 + h1 + h2 + h3;
    ps[t] = tot;
    __syncthreads();
    for (int off = 1; off < 256; off <<= 1) {
        int u = (t >= off) ? ps[t - off] : 0;
        __syncthreads();
        ps[t] += u;
        __syncthreads();
    }
    int ex = ps[t] - tot;
    prefix[b0] = ex;
    prefix[b0 + 1] = ex + h0;
    prefix[b0 + 2] = ex + h0 + h1;
    prefix[b0 + 3] = ex + h0 + h1 + h2;
    __syncthreads();
    for (int b = t; b < 1024; b += 256) {
        int c = hist[b];
        if (c > 0 && b < NB) baseg[b] = atomicAdd(&bcursor[b << 4], c);
        hist[b] = prefix[b];
    }
    __syncthreads();
    for (int i = t; i < cnt; i += 256) {
        unsigned pk = stage[i];
        int p = atomicAdd(&hist[pk >> 22], 1);
        stage2[p] = pk;
    }
    __syncthreads();
    for (int i = t; i < cnt; i += 256) {
        unsigned pk = stage2[i];
        unsigned b = pk >> 22;
        packed[baseg[b] + (i - prefix[b])] = pk;
    }
}

// ---------------- per-bucket CSR finalize: writes epk=(dst<<16)|src, rowptr, dinv ----------------
__global__ __launch_bounds__(256) void k_bfinal(const unsigned* __restrict__ packed,
                                                const int* __restrict__ bbase,
                                                unsigned* __restrict__ epk,
                                                int* __restrict__ rowptr,
                                                float* __restrict__ dinv) {
    __shared__ unsigned pk[CAPE];
    __shared__ unsigned outv[CAPE];
    __shared__ int hcnt[64], hoff[64], hcur[64];
    int b = blockIdx.x;
    int base = bbase[b];
    int cnt = bbase[b + 1] - base;
    if (cnt > CAPE) cnt = CAPE;
    int t = threadIdx.x;
    for (int i = t; i < cnt; i += 256) pk[i] = packed[base + i];
    if (t < 64) hcnt[t] = 0;
    __syncthreads();
    for (int i = t; i < cnt; i += 256) atomicAdd(&hcnt[(pk[i] >> 16) & 63u], 1);
    __syncthreads();
    if (t == 0) {
        int run = 0;
        for (int i = 0; i < 64; ++i) { hoff[i] = run; hcur[i] = run; run += hcnt[i]; }
    }
    __syncthreads();
    if (t < 64) {
        int node = b * 64 + t;
        if (node < NN) {
            rowptr[node] = base + hoff[t];
            dinv[node] = rsqrtf((float)(hcnt[t] + 1));
        }
    }
    for (int i = t; i < cnt; i += 256) {
        unsigned v = pk[i] & 0x3FFFFFu;            // (dlocal<<16)|src
        int lpos = atomicAdd(&hcur[v >> 16], 1);
        outv[lpos] = v;
    }
    __syncthreads();
    const unsigned dbase = ((unsigned)(b * 64)) << 16;
    for (int i = t; i < cnt; i += 256)
        epk[base + i] = dbase + outv[i];           // (dst<<16)|src
}

// ---------------- merged prep: edge-parallel epk rewrite (fp16 weight) + weight transpose/bf16 ----------------
#define PREP_EBLKS ((NE + 255) / 256)   // 6250
__global__ void k_prep(const float* __restrict__ dinv, unsigned* __restrict__ epk,
                       const float* __restrict__ W1, const float* __restrict__ W2,
                       unsigned short* __restrict__ W1t, unsigned short* __restrict__ W2t) {
    int bid = blockIdx.x;
    if (bid < PREP_EBLKS) {
        int e = bid * 256 + threadIdx.x;
        if (e < NE) {
            unsigned pe = epk[e];
            unsigned s = pe & 0xFFFFu;
            unsigned d = pe >> 16;
            epk[e] = ((unsigned)f2h(dinv[s] * dinv[d]) << 16) | s;
        }
    } else {
        int i = (bid - PREP_EBLKS) * 256 + threadIdx.x;
        if (i < 512 * 128) {
            int k = i >> 7, n = i & 127;
            W1t[n * 512 + k] = f2bf(W1[i]);
        }
        if (i < 128 * 128) {
            int k = i >> 7, n = i & 127;
            W2t[n * 128 + k] = f2bf(W2[i]);
        }
    }
}

// ---------------- GEMM1 (layer1): A f32 [M][512] @ W1t^T(bf16) -> Cb[4][NN][32] fp16 ----------------
__global__ __launch_bounds__(256) void k_gemm1(const float* __restrict__ A,
                                               const unsigned short* __restrict__ Wt,
                                               unsigned short* __restrict__ Cb,
                                               int M, int K) {
    __shared__ unsigned short As[64][72];
    __shared__ unsigned short Bs[128][72];
    const int tid = threadIdx.x;
    const int m0 = blockIdx.x * 64;
    const int w = tid >> 6;
    const int lane = tid & 63;
    const int cr = lane & 15;
    const int half = lane >> 4;
    const int arow = tid >> 2;
    const int akseg = (tid & 3) << 4;
    const int brow = tid >> 1;
    const int bkseg = (tid & 1) << 5;

    f32x4 acc[8];
#pragma unroll
    for (int n = 0; n < 8; ++n) acc[n] = (f32x4){0.f, 0.f, 0.f, 0.f};

    for (int kc = 0; kc < K; kc += 64) {
        float4 va[4];
        int gm = m0 + arow;
        if (gm < M) {
            const float* ap = A + (size_t)gm * K + kc + akseg;
#pragma unroll
            for (int i = 0; i < 4; ++i) va[i] = ((const float4*)ap)[i];
        } else {
#pragma unroll
            for (int i = 0; i < 4; ++i) va[i] = make_float4(0.f, 0.f, 0.f, 0.f);
        }
        uint4 q0, q1;
        q0.x = packbf(va[0].x, va[0].y); q0.y = packbf(va[0].z, va[0].w);
        q0.z = packbf(va[1].x, va[1].y); q0.w = packbf(va[1].z, va[1].w);
        q1.x = packbf(va[2].x, va[2].y); q1.y = packbf(va[2].z, va[2].w);
        q1.z = packbf(va[3].x, va[3].y); q1.w = packbf(va[3].z, va[3].w);
        *(uint4*)(&As[arow][akseg]) = q0;
        *(uint4*)(&As[arow][akseg + 8]) = q1;
        {
            const unsigned short* wp = Wt + (size_t)brow * K + kc + bkseg;
            uint4* bp = (uint4*)(&Bs[brow][bkseg]);
#pragma unroll
            for (int i = 0; i < 4; ++i) bp[i] = ((const uint4*)wp)[i];
        }
        __syncthreads();
        const int wrow = w << 4;
#pragma unroll
        for (int ks = 0; ks < 2; ++ks) {
            bf16x8 af = *(const bf16x8*)(&As[wrow + cr][ks * 32 + half * 8]);
#pragma unroll
            for (int n = 0; n < 8; ++n) {
                bf16x8 bfr = *(const bf16x8*)(&Bs[n * 16 + cr][ks * 32 + half * 8]);
                acc[n] = __builtin_amdgcn_mfma_f32_16x16x32_bf16(af, bfr, acc[n], 0, 0, 0);
            }
        }
        __syncthreads();
    }
#pragma unroll
    for (int n = 0; n < 8; ++n) {
        int col = n * 16 + cr;
        size_t cbase = (size_t)(col >> 5) * NN * 32 + (col & 31);
#pragma unroll
        for (int reg = 0; reg < 4; ++reg) {
            int gr = m0 + (w << 4) + half * 4 + reg;
            if (gr < M) Cb[cbase + (size_t)gr * 32] = f2h(acc[n][reg]);
        }
    }
}

// ---------------- GEMM2 (layer2): A fp16 [M][128], BN+ReLU inline -> bf16 MFMA -> Cb fp16 ----------------
__global__ __launch_bounds__(256) void k_gemm2(const unsigned short* __restrict__ A,
                                               const unsigned short* __restrict__ Wt,
                                               const float* __restrict__ st,
                                               const float* __restrict__ gam,
                                               const float* __restrict__ beta,
                                               unsigned short* __restrict__ Cb,
                                               int M) {
    __shared__ unsigned short As[64][72];
    __shared__ unsigned short Bs[128][72];
    __shared__ float scs[128], shs[128];
    const int tid = threadIdx.x;
    const int m0 = blockIdx.x * 64;
    const int w = tid >> 6;
    const int lane = tid & 63;
    const int cr = lane & 15;
    const int half = lane >> 4;
    const int arow = tid >> 2;
    const int akseg = (tid & 3) << 4;
    const int brow = tid >> 1;
    const int bkseg = (tid & 1) << 5;

    if (tid < 128) {   // inline BN finalize
        const float invn = 1.0f / (float)NN;
        float mu = st[tid] * invn;
        float var = fmaf(-mu, mu, st[tid + 128] * invn);
        float s = gam[tid] * rsqrtf(var + EPSBN);
        scs[tid] = s;
        shs[tid] = fmaf(-mu, s, beta[tid]);
    }

    f32x4 acc[8];
#pragma unroll
    for (int n = 0; n < 8; ++n) acc[n] = (f32x4){0.f, 0.f, 0.f, 0.f};

    for (int kc = 0; kc < 128; kc += 64) {
        uint4 q0 = {0, 0, 0, 0}, q1 = {0, 0, 0, 0};
        int gm = m0 + arow;
        if (gm < M) {
            const uint4* ap = (const uint4*)(A + (size_t)gm * 128 + kc + akseg);
            q0 = ap[0];
            q1 = ap[1];
        }
        if (kc == 0) __syncthreads();  // scs/shs ready
        int kb = kc + akseg;
        unsigned qq[8] = {q0.x, q0.y, q0.z, q0.w, q1.x, q1.y, q1.z, q1.w};
#pragma unroll
        for (int j = 0; j < 8; ++j) {
            int k = kb + j * 2;
            f16x2 p = __builtin_bit_cast(f16x2, qq[j]);
            float lo = fmaxf(fmaf((float)p.x, scs[k], shs[k]), 0.f);
            float hi = fmaxf(fmaf((float)p.y, scs[k + 1], shs[k + 1]), 0.f);
            qq[j] = packbf(lo, hi);
        }
        *(uint4*)(&As[arow][akseg])     = make_uint4(qq[0], qq[1], qq[2], qq[3]);
        *(uint4*)(&As[arow][akseg + 8]) = make_uint4(qq[4], qq[5], qq[6], qq[7]);
        {
            const unsigned short* wp = Wt + (size_t)brow * 128 + kc + bkseg;
            uint4* bp = (uint4*)(&Bs[brow][bkseg]);
#pragma unroll
            for (int i = 0; i < 4; ++i) bp[i] = ((const uint4*)wp)[i];
        }
        __syncthreads();
        const int wrow = w << 4;
#pragma unroll
        for (int ks = 0; ks < 2; ++ks) {
            bf16x8 af = *(const bf16x8*)(&As[wrow + cr][ks * 32 + half * 8]);
#pragma unroll
            for (int n = 0; n < 8; ++n) {
                bf16x8 bfr = *(const bf16x8*)(&Bs[n * 16 + cr][ks * 32 + half * 8]);
                acc[n] = __builtin_amdgcn_mfma_f32_16x16x32_bf16(af, bfr, acc[n], 0, 0, 0);
            }
        }
        __syncthreads();
    }
#pragma unroll
    for (int n = 0; n < 8; ++n) {
        int col = n * 16 + cr;
        size_t cbase = (size_t)(col >> 5) * NN * 32 + (col & 31);
#pragma unroll
        for (int reg = 0; reg < 4; ++reg) {
            int gr = m0 + (w << 4) + half * 4 + reg;
            if (gr < M) Cb[cbase + (size_t)gr * 32] = f2h(acc[n][reg]);
        }
    }
}

// ---------------- column-blocked CSR gather (fp16 packed FMA) -> fp16 h, ONE chunk/dispatch ----------------
__global__ __launch_bounds__(256) void k_gather128b(const unsigned short* __restrict__ tb,
                                                    const int* __restrict__ rowptr,
                                                    const unsigned* __restrict__ epk,
                                                    const float* __restrict__ dinv,
                                                    const float* __restrict__ bias,
                                                    unsigned short* __restrict__ h,
                                                    int chunk) {
    int g = (blockIdx.x * 256 + threadIdx.x) >> 3;
    if (g >= NN) return;
    int lane8 = threadIdx.x & 7;
    int co = lane8 * 4;
    const unsigned short* tab = tb + (size_t)chunk * NN * 32;
    int beg = rowptr[g], end = rowptr[g + 1];
    float dd = dinv[g];
    uint2 sv = *(const uint2*)(tab + (size_t)g * 32 + co);
    float4 bv = *(const float4*)(bias + chunk * 32 + co);
    f16 wsh = (f16)(dd * dd);
    f16x2 ws2 = {wsh, wsh};
    f16x2 b01 = {(f16)bv.x, (f16)bv.y};
    f16x2 b23 = {(f16)bv.z, (f16)bv.w};
    f16x2 acc01 = __builtin_bit_cast(f16x2, sv.x) * ws2 + b01;
    f16x2 acc23 = __builtin_bit_cast(f16x2, sv.y) * ws2 + b23;
    // cooperative epk load + shfl broadcast + prefetch
    int idx0 = beg + lane8;
    unsigned pe = (idx0 < end) ? epk[idx0] : 0u;
    for (int base = beg; base < end; base += 8) {
        int nidx = base + 8 + lane8;
        unsigned pe_next = (nidx < end) ? epk[nidx] : 0u;
#pragma unroll
        for (int j = 0; j < 8; ++j) {
            unsigned pj = __shfl(pe, j, 8);
            f16 wh = __builtin_bit_cast(f16, (unsigned short)(pj >> 16));
            f16x2 ww = {wh, wh};
            int s = (int)(pj & 0xFFFFu);
            uint2 v = *(const uint2*)(tab + (size_t)s * 32 + co);
            acc01 += __builtin_bit_cast(f16x2, v.x) * ww;   // v_pk_fma_f16
            acc23 += __builtin_bit_cast(f16x2, v.y) * ww;
        }
        pe = pe_next;
    }
    uint2 o;
    o.x = __builtin_bit_cast(unsigned, acc01);
    o.y = __builtin_bit_cast(unsigned, acc23);
    *(uint2*)(h + (size_t)g * 128 + chunk * 32 + co) = o;
}

// ---------------- BN stats over fp16 h ----------------
__global__ __launch_bounds__(256) void k_bnstats(const unsigned short* __restrict__ h,
                                                 float* __restrict__ sums,
                                                 float* __restrict__ sumsq) {
    int c4 = (threadIdx.x & 31) * 4;
    int rg = threadIdx.x >> 5;
    float s1x = 0, s1y = 0, s1z = 0, s1w = 0;
    float s2x = 0, s2y = 0, s2z = 0, s2w = 0;
    for (int r = blockIdx.x * 8 + rg; r < NN; r += gridDim.x * 8) {
        ushort4 u = *(const ushort4*)(h + (size_t)r * 128 + c4);
        float vx = h2f(u.x), vy = h2f(u.y), vz = h2f(u.z), vw = h2f(u.w);
        s1x += vx; s1y += vy; s1z += vz; s1w += vw;
        s2x = fmaf(vx, vx, s2x);
        s2y = fmaf(vy, vy, s2y);
        s2z = fmaf(vz, vz, s2z);
        s2w = fmaf(vw, vw, s2w);
    }
    __shared__ float l1[256][4];
    __shared__ float l2[256][4];
    l1[threadIdx.x][0] = s1x; l1[threadIdx.x][1] = s1y;
    l1[threadIdx.x][2] = s1z; l1[threadIdx.x][3] = s1w;
    l2[threadIdx.x][0] = s2x; l2[threadIdx.x][1] = s2y;
    l2[threadIdx.x][2] = s2z; l2[threadIdx.x][3] = s2w;
    __syncthreads();
    if (rg == 0) {
        int lane = threadIdx.x & 31;
#pragma unroll
        for (int gg = 1; gg < 8; ++gg) {
            int o = gg * 32 + lane;
            s1x += l1[o][0]; s1y += l1[o][1]; s1z += l1[o][2]; s1w += l1[o][3];
            s2x += l2[o][0]; s2y += l2[o][1]; s2z += l2[o][2]; s2w += l2[o][3];
        }
        atomicAdd(&sums[c4 + 0], s1x);
        atomicAdd(&sums[c4 + 1], s1y);
        atomicAdd(&sums[c4 + 2], s1z);
        atomicAdd(&sums[c4 + 3], s1w);
        atomicAdd(&sumsq[c4 + 0], s2x);
        atomicAdd(&sumsq[c4 + 1], s2y);
        atomicAdd(&sumsq[c4 + 2], s2z);
        atomicAdd(&sumsq[c4 + 3], s2w);
    }
}

// ---------------- small GEMM, fp16 A, BN+ReLU inline: C[M][8] = relu(bn(A)) @ W3 ----------------
__global__ __launch_bounds__(256) void k_gemm8_bn(const unsigned short* __restrict__ A,
                                                  const float* __restrict__ W,
                                                  const float* __restrict__ st,
                                                  const float* __restrict__ gam,
                                                  const float* __restrict__ beta,
                                                  float* __restrict__ C, int M) {
    __shared__ float Ws[128 * 8];
    __shared__ float scs[128], shs[128];
    int tid = threadIdx.x;
    for (int i = tid; i < 128 * 8; i += 256) Ws[i] = W[i];
    if (tid < 128) {
        const float invn = 1.0f / (float)NN;
        float mu = st[tid] * invn;
        float var = fmaf(-mu, mu, st[tid + 128] * invn);
        float s = gam[tid] * rsqrtf(var + EPSBN);
        scs[tid] = s;
        shs[tid] = fmaf(-mu, s, beta[tid]);
    }
    __syncthreads();
    int m = blockIdx.x * 32 + (tid >> 3);
    int n = tid & 7;
    if (m >= M) return;
    const unsigned short* a = A + (size_t)m * 128;
    float s = 0.0f;
#pragma unroll
    for (int k = 0; k < 128; k += 8) {
        uint4 q = *(const uint4*)(a + k);
        unsigned qq[4] = {q.x, q.y, q.z, q.w};
#pragma unroll
        for (int j = 0; j < 4; ++j) {
            int kk = k + j * 2;
            f16x2 p = __builtin_bit_cast(f16x2, qq[j]);
            float lo = fmaxf(fmaf((float)p.x, scs[kk], shs[kk]), 0.f);
            float hi = fmaxf(fmaf((float)p.y, scs[kk + 1], shs[kk + 1]), 0.f);
            s = fmaf(lo, Ws[kk * 8 + n], s);
            s = fmaf(hi, Ws[(kk + 1) * 8 + n], s);
        }
    }
    C[(size_t)m * 8 + n] = s;
}

// ---------------- CSR gather (8 cols) + fused log_softmax, shfl + prefetch ----------------
__global__ __launch_bounds__(256) void k_gather8_lsm(const float* __restrict__ t,
                                                     const int* __restrict__ rowptr,
                                                     const unsigned* __restrict__ epk,
                                                     const float* __restrict__ dinv,
                                                     const float* __restrict__ bias,
                                                     float* __restrict__ out) {
    int g = (blockIdx.x * 256 + threadIdx.x) >> 3;
    if (g >= NN) return;
    int c = threadIdx.x & 7;
    int beg = rowptr[g], end = rowptr[g + 1];
    float dd = dinv[g];
    float acc = fmaf(t[(size_t)g * 8 + c], dd * dd, bias[c]);
    int idx0 = beg + c;
    unsigned pe = (idx0 < end) ? epk[idx0] : 0u;
    for (int base = beg; base < end; base += 8) {
        int nidx = base + 8 + c;
        unsigned pe_next = (nidx < end) ? epk[nidx] : 0u;
#pragma unroll
        for (int j = 0; j < 8; ++j) {
            unsigned pj = __shfl(pe, j, 8);
            float w = h2f((unsigned short)(pj >> 16));
            int s = (int)(pj & 0xFFFFu);
            acc = fmaf(t[(size_t)s * 8 + c], w, acc);
        }
        pe = pe_next;
    }
    float mx = acc;
#pragma unroll
    for (int m = 1; m < 8; m <<= 1) mx = fmaxf(mx, __shfl_xor(mx, m, 8));
    float ex = expf(acc - mx);
    float se = ex;
#pragma unroll
    for (int m = 1; m < 8; m <<= 1) se += __shfl_xor(se, m, 8);
    out[(size_t)g * 8 + c] = acc - (logf(se) + mx);
}

extern "C" void kernel_launch(void* const* d_in, const int* in_sizes, int n_in,
                              void* d_out, int out_size, void* d_ws, size_t ws_size,
                              hipStream_t stream) {
    const float* x     = (const float*)d_in[0];
    const int*   eidx  = (const int*)d_in[1];
    const float* W1    = (const float*)d_in[2];
    const float* b1    = (const float*)d_in[3];
    const float* W2    = (const float*)d_in[4];
    const float* b2    = (const float*)d_in[5];
    const float* W3    = (const float*)d_in[6];
    const float* b3    = (const float*)d_in[7];
    const float* g1    = (const float*)d_in[8];
    const float* beta1 = (const float*)d_in[9];
    const float* g2    = (const float*)d_in[10];
    const float* beta2 = (const float*)d_in[11];
    float* out = (float*)d_out;

    const int* src = eidx;
    const int* dst = eidx + NE;

    char* ws = (char*)d_ws;
    int*   bcnt    = (int*)ws;            ws += 51200 * 4;
    int*   bbase   = (int*)ws;            ws += 2048 * 4;
    int*   rowptr  = (int*)ws;            ws += 51200 * 4;
    float* dinv    = (float*)ws;          ws += 51200 * 4;
    float* st      = (float*)ws;          ws += 512 * 4;     // st1 | st2
    unsigned* epk  = (unsigned*)ws;       ws += (size_t)NE * 4;
    unsigned short* W1t = (unsigned short*)ws;  ws += 128 * 512 * 2;
    unsigned short* W2t = (unsigned short*)ws;  ws += 128 * 128 * 2;
    unsigned short* Ab  = (unsigned short*)ws;  ws += (size_t)4 * NN * 32 * 2;  // blocked fp16
    unsigned short* Bf  = (unsigned short*)ws;  ws += (size_t)NN * 128 * 2;     // fp16 h
    float* C       = (float*)ws;
    unsigned* packed = (unsigned*)Ab;  // overlap: consumed by k_bfinal before gemm1 writes Ab

    // ---- CSR build ----
    k_zero<<<(NB * PAD + 255) / 256, 256, 0, stream>>>(bcnt, st);
    k_hist<<<NBLK, 256, 0, stream>>>(dst, bcnt);
    k_bscan<<<1, 1024, 0, stream>>>(bcnt, bbase, rowptr);
    k_part<<<NBLK, 256, 0, stream>>>(src, dst, bcnt, packed);
    k_bfinal<<<NB, 256, 0, stream>>>(packed, bbase, epk, rowptr, dinv);
    k_prep<<<PREP_EBLKS + 256, 256, 0, stream>>>(dinv, epk, W1, W2, W1t, W2t);

    const int ggrid = (NN * 8 + 255) / 256;

    // ---- layer 1 ----
    k_gemm1<<<(NN + 63) / 64, 256, 0, stream>>>(x, W1t, Ab, NN, DIN);
    for (int ch = 0; ch < 4; ++ch)
        k_gather128b<<<ggrid, 256, 0, stream>>>(Ab, rowptr, epk, dinv, b1, Bf, ch);
    k_bnstats<<<512, 256, 0, stream>>>(Bf, st, st + 128);

    // ---- layer 2 (BN1+ReLU inline in A-staging) ----
    k_gemm2<<<(NN + 63) / 64, 256, 0, stream>>>(Bf, W2t, st, g1, beta1, Ab, NN);
    for (int ch = 0; ch < 4; ++ch)
        k_gather128b<<<ggrid, 256, 0, stream>>>(Ab, rowptr, epk, dinv, b2, Bf, ch);
    k_bnstats<<<512, 256, 0, stream>>>(Bf, st + 256, st + 384);

    // ---- layer 3 (BN2+ReLU inline) ----
    k_gemm8_bn<<<(NN + 31) / 32, 256, 0, stream>>>(Bf, W3, st + 256, g2, beta2, C, NN);
    k_gather8_lsm<<<(NN * 8 + 255) / 256, 256, 0, stream>>>(C, rowptr, epk, dinv, b3, out);
}